// Round 10
// baseline (97.755 us; speedup 1.0000x reference)
//
#include <hip/hip_runtime.h>
#include <hip/hip_cooperative_groups.h>

namespace cg = cooperative_groups;

#define HH 48
#define WW 48
#define HW 2304   // 48*48
#define NB 8      // N
#define CB 4      // COLOR
#define TB 3      // RGB
#define NCHUNK (4 * NB * TB * (HW / 64))   // 3456

// pred_img_i[b,n,t,y,x] = 0.25 * sum_c sum_s kw[b,n,s,t,y,x] *
//     sum_{i,j in KxK} c1[..cur_s+i..]*c2[..cur_s+j..] * F[c, y+i-3, x+j-3]
// s=0:K=7,cur=9  s=1:K=5,cur=4  s=2:K=3,cur=1  s=3:K=1,cur=0
//
// R10: cooperative persistent kernel. R7 body (phased, thin threads, LDS
// c-reduce) in a grid-stride loop over 3456 chunks; grid.sync(); then the
// n-mean phase in the same kernel. Removes the dependent mean_fb launch.
// Lessons kept: no float2 (R3/R9), no launch_bounds cap (R5), no atomics+memset (R8).

__device__ __forceinline__ void do_chunk(
    const float* __restrict__ frames, const float* __restrict__ core,
    const float* __restrict__ kw, float* __restrict__ out,
    int blk, int tix, int c, int p64, float lds[CB][64])
{
    const int pc = blk % (HW / 64);
    int rem = blk / (HW / 64);
    const int t = rem % TB; rem /= TB;
    const int n = rem % NB;
    const int b = rem / NB;
    const int pix = pc * 64 + p64;
    const int x = pix % WW;
    const int y = pix / WW;

    const float* cp = core + ((size_t)b * 3072 + (size_t)((n * 32) * CB + c) * 3 + t) * HW + pix;

    // phase 1: column weights bv[16]
    float bv[16];
    #pragma unroll
    for (int q = 0; q < 16; ++q)
        bv[q] = cp[(size_t)((q + 16) * 12) * HW];

    // x clamps/masks hoisted out of the row loop
    int   xoff[7];
    float xmsk[7];
    #pragma unroll
    for (int j = 0; j < 7; ++j) {
        const int xx = x + j - 3;
        xoff[j] = min(max(xx, 0), WW - 1);
        xmsk[j] = ((xx >= 0) & (xx < WW)) ? 1.f : 0.f;
    }

    const float* fb = frames + ((size_t)(b * NB + n) * CB + c) * HW;

    // phase 2: per-row inner sums (fp[] transient)
    float in7[7], in5[5], in3[3], f1 = 0.f;
    #pragma unroll
    for (int i = 0; i < 7; ++i) {
        const int yy = y + i - 3;
        const float ymsk = ((yy >= 0) & (yy < HH)) ? 1.f : 0.f;
        const float* frow = fb + min(max(yy, 0), HH - 1) * WW;
        float fp[7];
        #pragma unroll
        for (int j = 0; j < 7; ++j)
            fp[j] = frow[xoff[j]] * (ymsk * xmsk[j]);   // branchless zero-pad
        float s7 = 0.f;
        #pragma unroll
        for (int j = 0; j < 7; ++j) s7 = fmaf(bv[9 + j], fp[j], s7);
        in7[i] = s7;
        if (i >= 1 && i <= 5) {
            float s5 = 0.f;
            #pragma unroll
            for (int j = 0; j < 5; ++j) s5 = fmaf(bv[4 + j], fp[1 + j], s5);
            in5[i - 1] = s5;
        }
        if (i >= 2 && i <= 4) {
            float s3 = 0.f;
            #pragma unroll
            for (int j = 0; j < 3; ++j) s3 = fmaf(bv[1 + j], fp[2 + j], s3);
            in3[i - 2] = s3;
        }
        if (i == 3) f1 = bv[0] * fp[3];
    }

    // keep a[]/kw loads out of phase 2 (peak-pressure control)
    __builtin_amdgcn_sched_barrier(0);

    // phase 3: row weights + kernel_weight, final dots
    float a[16];
    #pragma unroll
    for (int q = 0; q < 16; ++q)
        a[q] = cp[(size_t)(q * 12) * HW];

    const float* kwp = kw + ((size_t)(b * NB + n) * 12 + t) * HW + pix;
    const float kw0 = kwp[0];
    const float kw1 = kwp[(size_t)3 * HW];
    const float kw2 = kwp[(size_t)6 * HW];
    const float kw3 = kwp[(size_t)9 * HW];

    float r7 = 0.f, r5 = 0.f, r3 = 0.f;
    #pragma unroll
    for (int i = 0; i < 7; ++i) r7 = fmaf(a[9 + i], in7[i], r7);
    #pragma unroll
    for (int i = 0; i < 5; ++i) r5 = fmaf(a[4 + i], in5[i], r5);
    #pragma unroll
    for (int i = 0; i < 3; ++i) r3 = fmaf(a[1 + i], in3[i], r3);
    const float r1 = a[0] * f1;

    const float val = fmaf(kw0, r7, fmaf(kw1, r5, fmaf(kw2, r3, kw3 * r1)));

    // LDS reduce over c
    lds[c][p64] = val;
    __syncthreads();
    if (tix < 64) {
        const float s4 = 0.25f * (lds[0][tix] + lds[1][tix] + lds[2][tix] + lds[3][tix]);
        out[((size_t)(b * NB + n) * TB + t) * HW + pc * 64 + tix] = s4;
    }
    __syncthreads();   // WAR guard: lds reused next grid-stride iteration
}

__global__ __launch_bounds__(256) void kconv_coop(
    const float* __restrict__ frames, const float* __restrict__ core,
    const float* __restrict__ kw, float* __restrict__ out, float* __restrict__ pm)
{
    const int tix = threadIdx.x;
    const int c   = tix >> 6;
    const int p64 = tix & 63;
    __shared__ float lds[CB][64];

    for (int blk = blockIdx.x; blk < NCHUNK; blk += gridDim.x)
        do_chunk(frames, core, kw, out, blk, tix, c, p64, lds);

    cg::this_grid().sync();

    // n-mean phase: pred_img[b,t,pix] = mean_n pred_img_i[b,n,t,pix]
    for (int tid = blockIdx.x * blockDim.x + tix; tid < 4 * TB * HW;
         tid += gridDim.x * blockDim.x) {
        const int pix3 = tid % (TB * HW);
        const int b = tid / (TB * HW);
        float s = 0.f;
        #pragma unroll
        for (int n = 0; n < NB; ++n)
            s += out[(size_t)((b * NB + n) * TB) * HW + pix3];
        pm[tid] = s * 0.125f;
    }
}

// ---- fallback: proven R7 two-kernel path ----
__global__ __launch_bounds__(256) void kconv_fused(
    const float* __restrict__ frames, const float* __restrict__ core,
    const float* __restrict__ kw, float* __restrict__ out)
{
    const int tix = threadIdx.x;
    __shared__ float lds[CB][64];
    do_chunk(frames, core, kw, out, blockIdx.x, tix, tix >> 6, tix & 63, lds);
}

__global__ __launch_bounds__(256) void mean_fb(
    const float* __restrict__ pii, float* __restrict__ pm)
{
    const int tid = blockIdx.x * blockDim.x + threadIdx.x;  // 27648
    if (tid >= 4 * TB * HW) return;
    const int pix3 = tid % (TB * HW);
    const int b = tid / (TB * HW);
    float s = 0.f;
    #pragma unroll
    for (int n = 0; n < NB; ++n)
        s += pii[(size_t)((b * NB + n) * TB) * HW + pix3];
    pm[tid] = s * 0.125f;
}

extern "C" void kernel_launch(void* const* d_in, const int* in_sizes, int n_in,
                              void* d_out, int out_size, void* d_ws, size_t ws_size,
                              hipStream_t stream) {
    const float* frames = (const float*)d_in[0];
    const float* core   = (const float*)d_in[1];
    const float* kw     = (const float*)d_in[2];
    float* out = (float*)d_out;                  // pred_img_i: 221184 floats
    float* pm  = out + (size_t)4 * NB * TB * HW; // pred_img:   27648 floats

    // size the cooperative grid to guaranteed co-residency (non-stream queries,
    // graph-capture safe)
    int perCU = 0, numCU = 0, dev = 0;
    (void)hipGetDevice(&dev);
    hipError_t q1 = hipOccupancyMaxActiveBlocksPerMultiprocessor(&perCU, kconv_coop, 256, 0);
    hipError_t q2 = hipDeviceGetAttribute(&numCU, hipDeviceAttributeMultiprocessorCount, dev);

    if (q1 == hipSuccess && q2 == hipSuccess && perCU > 0 && numCU > 0) {
        int grid = perCU * numCU;
        if (grid > NCHUNK) grid = NCHUNK;
        void* args[] = { (void*)&frames, (void*)&core, (void*)&kw, (void*)&out, (void*)&pm };
        hipError_t le = hipLaunchCooperativeKernel((const void*)kconv_coop,
                                                   dim3(grid), dim3(256), args, 0, stream);
        if (le == hipSuccess) return;
    }

    // fallback: R7 structure
    kconv_fused<<<NCHUNK, 256, 0, stream>>>(frames, core, kw, out);
    mean_fb<<<(4 * TB * HW + 255) / 256, 256, 0, stream>>>(out, pm);
}

// Round 11
// 27.295 us; speedup vs baseline: 3.5815x; 3.5815x over previous
//
#include <hip/hip_runtime.h>

#define HH 48
#define WW 48
#define HW 2304   // 48*48
#define NB 8      // N
#define CB 4      // COLOR
#define TB 3      // RGB

// pred_img_i[b,n,t,y,x] = 0.25 * sum_c sum_s kw[b,n,s,t,y,x] *
//     sum_{i,j in KxK} c1[b,n,cur_s+i,c,t,y,x]*c2[b,n,cur_s+j,c,t,y,x]
//                      * F[b,n,c, y+i+p_s-3, x+j+p_s-3]
// s=0:K=7,cur=9  s=1:K=5,cur=4  s=2:K=3,cur=1  s=3:K=1,cur=0
//
// R11 = R7 verbatim (best measured: 27.26 us). Session map:
//  - thin threads (1 value/thread) beat float2 pairs twice (R3 34.8, R9 30.8)
//  - launch_bounds occupancy caps spill (R5 68.4)
//  - atomics+memset lose to a small dependent mean kernel (R8 30.4)
//  - cooperative persistent kernel destroys the flat schedule (R10 97.8)
//  - phased register structure (bv -> inner sums -> a,kw) keeps VGPR low
//    without caps; fused LDS c-reduce removes the part round-trip.
__global__ __launch_bounds__(256) void kconv_fused(
    const float* __restrict__ frames,   // (4, 8, 4, 48, 48)
    const float* __restrict__ core,     // (4, 3072, 48, 48)  ch=((n*32+q)*4+c)*3+t
    const float* __restrict__ kw,       // (4, 8, 4, 3, 48, 48)
    float* __restrict__ out)            // pred_img_i (4, 8, 3, 48, 48)
{
    const int blk = blockIdx.x;          // 4*8*3*36 = 3456
    const int pc  = blk % (HW / 64);     // 64-pixel chunk, 36 per image
    int rem = blk / (HW / 64);
    const int t = rem % TB; rem /= TB;
    const int n = rem % NB;
    const int b = rem / NB;
    const int tix = threadIdx.x;         // 0..255
    const int c   = tix >> 6;            // wave id = color
    const int p64 = tix & 63;
    const int pix = pc * 64 + p64;
    const int x = pix % WW;
    const int y = pix / WW;

    const float* cp = core + ((size_t)b * 3072 + (size_t)((n * 32) * CB + c) * 3 + t) * HW + pix;

    // phase 1: column weights bv[16]
    float bv[16];
    #pragma unroll
    for (int q = 0; q < 16; ++q)
        bv[q] = cp[(size_t)((q + 16) * 12) * HW];

    // x clamps/masks hoisted out of the row loop
    int   xoff[7];
    float xmsk[7];
    #pragma unroll
    for (int j = 0; j < 7; ++j) {
        const int xx = x + j - 3;
        xoff[j] = min(max(xx, 0), WW - 1);
        xmsk[j] = ((xx >= 0) & (xx < WW)) ? 1.f : 0.f;
    }

    const float* fb = frames + ((size_t)(b * NB + n) * CB + c) * HW;

    // phase 2: per-row inner sums (fp[] transient)
    float in7[7], in5[5], in3[3], f1 = 0.f;
    #pragma unroll
    for (int i = 0; i < 7; ++i) {
        const int yy = y + i - 3;
        const float ymsk = ((yy >= 0) & (yy < HH)) ? 1.f : 0.f;
        const float* frow = fb + min(max(yy, 0), HH - 1) * WW;
        float fp[7];
        #pragma unroll
        for (int j = 0; j < 7; ++j)
            fp[j] = frow[xoff[j]] * (ymsk * xmsk[j]);   // branchless zero-pad
        float s7 = 0.f;
        #pragma unroll
        for (int j = 0; j < 7; ++j) s7 = fmaf(bv[9 + j], fp[j], s7);
        in7[i] = s7;
        if (i >= 1 && i <= 5) {
            float s5 = 0.f;
            #pragma unroll
            for (int j = 0; j < 5; ++j) s5 = fmaf(bv[4 + j], fp[1 + j], s5);
            in5[i - 1] = s5;
        }
        if (i >= 2 && i <= 4) {
            float s3 = 0.f;
            #pragma unroll
            for (int j = 0; j < 3; ++j) s3 = fmaf(bv[1 + j], fp[2 + j], s3);
            in3[i - 2] = s3;
        }
        if (i == 3) f1 = bv[0] * fp[3];
    }

    // keep a[]/kw loads from being hoisted above (peak-pressure control)
    __builtin_amdgcn_sched_barrier(0);

    // phase 3: row weights + kernel_weight, final dots
    float a[16];
    #pragma unroll
    for (int q = 0; q < 16; ++q)
        a[q] = cp[(size_t)(q * 12) * HW];

    const float* kwp = kw + ((size_t)(b * NB + n) * 12 + t) * HW + pix;
    const float kw0 = kwp[0];
    const float kw1 = kwp[(size_t)3 * HW];
    const float kw2 = kwp[(size_t)6 * HW];
    const float kw3 = kwp[(size_t)9 * HW];

    float r7 = 0.f, r5 = 0.f, r3 = 0.f;
    #pragma unroll
    for (int i = 0; i < 7; ++i) r7 = fmaf(a[9 + i], in7[i], r7);
    #pragma unroll
    for (int i = 0; i < 5; ++i) r5 = fmaf(a[4 + i], in5[i], r5);
    #pragma unroll
    for (int i = 0; i < 3; ++i) r3 = fmaf(a[1 + i], in3[i], r3);
    const float r1 = a[0] * f1;

    const float val = fmaf(kw0, r7, fmaf(kw1, r5, fmaf(kw2, r3, kw3 * r1)));

    // LDS reduce over c (1 KB; 2 lanes/bank on write = free)
    __shared__ float lds[CB][64];
    lds[c][p64] = val;
    __syncthreads();
    if (tix < 64) {
        const float s = lds[0][tix] + lds[1][tix] + lds[2][tix] + lds[3][tix];
        out[((size_t)(b * NB + n) * TB + t) * HW + pc * 64 + tix] = 0.25f * s;
    }
}

// pred_img[b,t,pix] = mean_n pred_img_i[b,n,t,pix]
__global__ __launch_bounds__(256) void mean_fb(
    const float* __restrict__ pii, float* __restrict__ pm)
{
    const int tid = blockIdx.x * blockDim.x + threadIdx.x;  // 27648
    if (tid >= 4 * TB * HW) return;
    const int pix3 = tid % (TB * HW);
    const int b = tid / (TB * HW);
    float s = 0.f;
    #pragma unroll
    for (int n = 0; n < NB; ++n)
        s += pii[(size_t)((b * NB + n) * TB) * HW + pix3];
    pm[tid] = s * 0.125f;
}

extern "C" void kernel_launch(void* const* d_in, const int* in_sizes, int n_in,
                              void* d_out, int out_size, void* d_ws, size_t ws_size,
                              hipStream_t stream) {
    const float* frames = (const float*)d_in[0];
    const float* core   = (const float*)d_in[1];
    const float* kw     = (const float*)d_in[2];
    float* out = (float*)d_out;                 // pred_img_i: 221184 floats
    float* pm  = out + 4 * NB * TB * HW;        // pred_img:   27648 floats

    kconv_fused<<<4 * NB * TB * (HW / 64), 256, 0, stream>>>(frames, core, kw, out);
    mean_fb<<<(4 * TB * HW + 255) / 256, 256, 0, stream>>>(out, pm);
}